// Round 9
// baseline (1124.253 us; speedup 1.0000x reference)
//
#include <hip/hip_runtime.h>
#include <hip/hip_bf16.h>
#include <math.h>

typedef _Float16 half8 __attribute__((ext_vector_type(8)));
typedef _Float16 half4v __attribute__((ext_vector_type(4)));
typedef float floatx4 __attribute__((ext_vector_type(4)));

// exact-erf gelu via A&S 7.1.26 approx (|err_erf| <= 1.5e-7, invisible at f16)
__device__ __forceinline__ float gelu_f(float x){
    float z = fabsf(x) * 0.70710678118654752440f;
    float t = 1.0f / (1.0f + 0.3275911f * z);
    float poly = ((((1.061405429f*t - 1.453152027f)*t + 1.421413741f)*t
                   - 0.284496736f)*t + 0.254829592f)*t;
    float erfz = 1.0f - poly * __expf(-z*z);
    float erfx = __builtin_copysignf(erfz, x);
    return 0.5f * x * (1.0f + erfx);
}

typedef __attribute__((address_space(1))) const unsigned int gu32;
typedef __attribute__((address_space(3))) unsigned int lu32;
__device__ __forceinline__ void gl16(const void* g, void* l){
    __builtin_amdgcn_global_load_lds((gu32*)g, (lu32*)l, 16, 0, 0);
}

// ---------------- generic f16 MFMA GEMM (BK=32, 2-phase prefetch) ----------------
// C[i][j] = sum_k A[i][k] * Bt[j][k]   (A,Bt rows 16B-aligned, K % 32 == 0,
// all K-tail/pad regions of A,Bt are ZERO; OOB rows readable garbage)
// 2-phase (T3-minimum): STAGE(next buf) issued BEFORE ds_read+MFMA of current,
// single __syncthreads per K-step (its vmcnt drain lands late -> latency hidden).
// LDS swizzle (rule #21): linear LDS dest (gload_lds), SOURCE chunk
// pre-swizzled (lane&3)^((lane>>3)&3); reader col (lb^((la>>1)&3))*8.
// SM: 0 row store C[i*ldc+j]
//     1 trans store C[j*ldc+i..i+3] (EPI bits: 1 gelu, 2 +C-old, 4 +D, 8 dual Xc)
//     2 spec-dual (fwd Legendre): C row j signed, C2 row j^1
//     3 dhconv-split: j<181 -> row i col j ; j>=181 -> row i+256 col j-181
//     4 DFT->xfm fused: xfm[m][2c+s][192] from i=(c,h), j=(s,m)
// Fusion rule (R5): epilogue may deviate from row-major ONLY if each block's
// output footprint covers whole 64B lines.
struct GemmP {
    const _Float16* A; const _Float16* Bt; void* C; void* C2; const _Float16* D;
    long long aBS, bBS, cBS;
    int lda, ldb, ldc, ldd;
    int I, J, K;
};

template<int SM, int EPI, typename CT, bool GSW>
__global__ __launch_bounds__(256, 3) void mfma_gemm(GemmP p){
    __shared__ __align__(16) _Float16 As[2][128][32];
    __shared__ __align__(16) _Float16 Bs[2][128][32];
    const int tid = threadIdx.x, lane = tid & 63, wave = tid >> 6;
    const int wr = wave >> 1, wc = wave & 1;
    const int bj = GSW ? blockIdx.y : blockIdx.x;
    const int bi = GSW ? blockIdx.x : blockIdx.y;
    const int bz = blockIdx.z;
    const _Float16* A  = p.A  + (long long)bz * p.aBS;
    const _Float16* Bt = p.Bt + (long long)bz * p.bBS;
    CT* C = (CT*)p.C + (long long)bz * p.cBS;

    const int srow = wave*16 + (lane >> 2);
    const int cg = ((lane & 3) ^ ((lane >> 3) & 3)) * 8;   // inverse-swizzled source chunk
    const _Float16* Ag = A  + (long long)(bi*128 + srow)*p.lda + cg;
    const _Float16* Bg = Bt + (long long)(bj*128 + srow)*p.ldb + cg;
    const long long a64 = (long long)64 * p.lda, b64 = (long long)64 * p.ldb;

    floatx4 acc[4][4];
    #pragma unroll
    for (int a=0;a<4;a++)
        #pragma unroll
        for (int b=0;b<4;b++) acc[a][b] = (floatx4){0.f,0.f,0.f,0.f};

    const int la = lane & 15, lb = lane >> 4;
    const int colr = (lb ^ ((la >> 1) & 3)) * 8;           // swizzled read col

    auto stage = [&](int buf, int k0){
        _Float16* AsW = &As[buf][0][0] + wave*512;
        _Float16* BsW = &Bs[buf][0][0] + wave*512;
        gl16(Ag + k0,       AsW);
        gl16(Ag + k0 + a64, AsW + 2048);
        gl16(Bg + k0,       BsW);
        gl16(Bg + k0 + b64, BsW + 2048);
    };

    stage(0, 0);
    __syncthreads();
    int cur = 0;
    for (int k0 = 0; k0 < p.K; k0 += 32){
        if (k0 + 32 < p.K) stage(cur ^ 1, k0 + 32);   // prefetch next tile (async)
        half8 af[4], bf[4];
        #pragma unroll
        for (int f=0; f<4; f++) af[f] = *(const half8*)&As[cur][wr*64 + f*16 + la][colr];
        #pragma unroll
        for (int f=0; f<4; f++) bf[f] = *(const half8*)&Bs[cur][wc*64 + f*16 + la][colr];
        #pragma unroll
        for (int mi=0; mi<4; mi++)
            #pragma unroll
            for (int nj=0; nj<4; nj++)
                acc[mi][nj] = __builtin_amdgcn_mfma_f32_16x16x32_f16(
                    af[mi], bf[nj], acc[mi][nj], 0, 0, 0);
        __syncthreads();   // drains prefetch (issued early) + orders buffer reuse
        cur ^= 1;
    }

    // epilogue. C/D: col = lane&15, row = (lane>>4)*4 + reg
    #pragma unroll
    for (int mi=0; mi<4; mi++){
        const int ibase = bi*128 + wr*64 + mi*16 + lb*4;
        #pragma unroll
        for (int nj=0; nj<4; nj++){
            const int j = bj*128 + wc*64 + nj*16 + la;
            if (j >= p.J) continue;
            if (SM == 0){
                #pragma unroll
                for (int r=0;r<4;r++){
                    int i = ibase + r;
                    if (i >= p.I) continue;
                    C[(long long)i*p.ldc + j] = (CT)acc[mi][nj][r];
                }
            } else if (SM == 2){
                _Float16* C2p = (_Float16*)p.C2 + (long long)bz*p.cBS;
                #pragma unroll
                for (int r=0;r<4;r++){
                    int i = ibase + r;
                    if (i >= p.I) continue;
                    float v = acc[mi][nj][r];
                    ((_Float16*)C)[(long long)i*p.ldc + j]   = (_Float16)((j & 1) ? -v : v);
                    C2p[(long long)i*p.ldc + (j ^ 1)]        = (_Float16)v;
                }
            } else if (SM == 3){
                const int row_add = (j < 181) ? 0 : 256;
                const int col = (j < 181) ? j : j - 181;
                #pragma unroll
                for (int r=0;r<4;r++){
                    int i = ibase + r;
                    if (i >= p.I) continue;
                    C[(long long)(i + row_add)*p.ldc + col] = (CT)acc[mi][nj][r];
                }
            } else if (SM == 4){
                // i = c*180+h (groups of 4 never cross c), j = s*181+m
                const int s = (j < 181) ? 0 : 1;
                const int m = j - s*181;
                const int c = ibase / 180, h0 = ibase % 180;
                half4v ov;
                #pragma unroll
                for (int r=0;r<4;r++) ov[r] = (_Float16)acc[mi][nj][r];
                *(half4v*)(void*)&((_Float16*)C)[(long long)m*98304 + (2*c + s)*192 + h0] = ov;
            } else { // SM == 1
                CT* cp = C + (long long)j*p.ldc + ibase;
                float v[4];
                #pragma unroll
                for (int r=0;r<4;r++) v[r] = acc[mi][nj][r];
                if (EPI & 2){
                    half4v old = *(const half4v*)(const void*)cp;
                    #pragma unroll
                    for (int r=0;r<4;r++) v[r] += (float)old[r];
                }
                if (EPI & 4){
                    #pragma unroll
                    for (int r=0;r<4;r++)
                        v[r] += (float)p.D[(long long)(ibase + r)*p.ldd + j];
                }
                if (EPI & 1){
                    #pragma unroll
                    for (int r=0;r<4;r++) v[r] = gelu_f(v[r]);
                }
                half4v ov;
                #pragma unroll
                for (int r=0;r<4;r++) ov[r] = (_Float16)v[r];
                *(half4v*)(void*)cp = ov;
                if (EPI & 8){
                    int h = j/360, w = j - h*360;
                    _Float16* xc = (_Float16*)p.C2;
                    #pragma unroll
                    for (int r=0;r<4;r++)
                        xc[(long long)(ibase + r)*69120 + h*384 + w] = ov[r];
                }
            }
        }
    }
}

// ---------------- setup / bridge kernels ----------------
// x f32 [c][hw] -> X_t f16 [hw][256] AND Xc f16 [(c*180+h)][384]
__global__ __launch_bounds__(256) void tx_k(const float* x, _Float16* X_t, _Float16* Xc){
    __shared__ _Float16 t[32][33];
    int p0 = blockIdx.x*32, c0 = blockIdx.y*32;
    int tx = threadIdx.x & 31, ty = threadIdx.x >> 5;
    #pragma unroll
    for (int q=0;q<4;q++){
        int c = c0 + ty + 8*q, hw = p0 + tx;
        _Float16 h = (_Float16)x[(long long)c*64800 + hw];
        t[ty+8*q][tx] = h;
        int hh = hw/360, w = hw - hh*360;
        Xc[((long long)c*180 + hh)*384 + w] = h;
    }
    __syncthreads();
    #pragma unroll
    for (int q=0;q<4;q++){
        int hw = p0 + ty + 8*q, c = c0 + tx;
        X_t[(long long)hw*256 + c] = t[tx][ty+8*q];
    }
}

// merged small setup: tw tables + Xc pad + P pad + 4 weight casts
__global__ __launch_bounds__(256) void setup_misc_k(
        const float* winner, const float* wfc1, const float* wfc2, const float* wout,
        _Float16* winner16, _Float16* wfc116, _Float16* wfc216, _Float16* wout16,
        _Float16* fwdTwT, _Float16* invTwT, _Float16* Xc, _Float16* P){
    int id = blockIdx.x*256 + threadIdx.x;
    if (id < 147456){
        {
            int j = id / 384, w = id % 384;
            float v = 0.f;
            if (j < 362 && w < 360){
                int m = (j < 181) ? j : j - 181;
                float ang = 6.28318530717958647692f * (float)((w*m) % 360) / 360.f;
                v = (j < 181) ? cosf(ang) : -sinf(ang);
            }
            fwdTwT[id] = (_Float16)v;
        }
        {
            int w = id / 384, k = id % 384;
            float v = 0.f;
            if (w < 360 && k < 362){
                int m = (k < 181) ? k : k - 181;
                float ang = 6.28318530717958647692f * (float)((w*m) % 360) / 360.f;
                float sc = (m == 0 || m == 180) ? (1.f/360.f) : (2.f/360.f);
                v = (k < 181) ? sc*cosf(ang) : -sc*sinf(ang);
            }
            invTwT[id] = (_Float16)v;
        }
        return;
    }
    int a = id - 147456;
    if (a < 138240){
        int row = a/3, c = a - 3*row;
        *(uint4*)&Xc[(long long)row*384 + 360 + c*8] = make_uint4(0u,0u,0u,0u);
        return;
    }
    int b = a - 138240;
    if (b < 556032){
        int row = b/6, c = b - 6*row;
        *(unsigned int*)&P[(long long)row*192 + 180 + c*2] = 0u;
        return;
    }
    int c = b - 556032;
    if (c < 131072){ winner16[c] = (_Float16)winner[c]; return; }
    c -= 131072;
    if (c < 262144){ wfc116[c] = (_Float16)wfc1[c]; return; }
    c -= 262144;
    if (c < 262144){ wfc216[c] = (_Float16)wfc2[c]; return; }
    c -= 262144;
    if (c < 32768){ wout16[c] = (_Float16)wout[c]; }
}

// pct [m][l][h] f32 -> pct16 [m][l][192] (pad zero)
__global__ __launch_bounds__(256) void cvt_pct_k(const float* in, _Float16* out){
    int id = blockIdx.x*256 + threadIdx.x;
    if (id >= 181*180*192) return;
    int m = id / 34560, r = id % 34560;
    int l = r / 192, h = r % 192;
    out[id] = (h < 180) ? (_Float16)in[(long long)m*32400 + l*180 + h] : (_Float16)0.f;
}

// pctinv [m][l][h] -> pctinvT [m][h][192(l)] (pad zero)
__global__ __launch_bounds__(256) void cvt_pctinvT_k(const float* in, _Float16* out){
    __shared__ float t[32][33];
    int m = blockIdx.z;
    int h0 = blockIdx.x*32, l0 = blockIdx.y*32;
    int tx = threadIdx.x & 31, ty = threadIdx.x >> 5;
    #pragma unroll
    for (int q=0;q<4;q++){
        int l = l0+ty+8*q, h = h0+tx;
        t[ty+8*q][tx] = (l < 180 && h < 180) ? in[(long long)m*32400 + l*180 + h] : 0.f;
    }
    __syncthreads();
    #pragma unroll
    for (int q=0;q<4;q++){
        int h = h0+ty+8*q, l = l0+tx;
        if (h < 180 && l < 192) out[(long long)m*34560 + h*192 + l] = (_Float16)t[tx][ty+8*q];
    }
}

// wspec [layer][ci][o][l][s] f32 -> Wc u32 view [((layer*180+l)*256+o)*256+ci] = half2(re,im)
__global__ __launch_bounds__(256) void build_wc_k(const float* wspec, _Float16* Wc){
    __shared__ unsigned int t[32][33];
    int o = blockIdx.x;
    int ci0 = blockIdx.y * 32;
    int z = blockIdx.z, layer = z / 6, l0 = (z % 6) * 32;
    int tx = threadIdx.x & 31, ty = threadIdx.x >> 5;
    unsigned int* Wc32 = (unsigned int*)Wc;
    #pragma unroll
    for (int q=0;q<4;q++){
        int ci = ci0 + ty + 8*q, l = l0 + tx;
        if (l < 180){
            const float2 v = *(const float2*)(wspec +
                ((long long)(layer*256 + ci))*92160 + (long long)o*360 + 2*l);
            union { unsigned int u; _Float16 h[2]; } pk;
            pk.h[0] = (_Float16)v.x; pk.h[1] = (_Float16)v.y;
            t[ty+8*q][tx] = pk.u;
        }
    }
    __syncthreads();
    #pragma unroll
    for (int q=0;q<4;q++){
        int l = l0 + ty + 8*q, ci = ci0 + tx;
        if (l < 180)
            Wc32[(((long long)layer*180 + l)*256 + o)*256 + ci] = t[tx][ty+8*q];
    }
}

// c2 [l][o2][m] (ld 181) -> c3 [m][o2][192(l)]
__global__ __launch_bounds__(256) void plm_k(const _Float16* c2, _Float16* c3){
    __shared__ _Float16 t[32][33];
    int cs = blockIdx.z;
    int m0 = blockIdx.x*32, l0 = blockIdx.y*32;
    int tx = threadIdx.x & 31, ty = threadIdx.x >> 5;
    #pragma unroll
    for (int q=0;q<4;q++){
        int l = l0+ty+8*q, m = m0+tx;
        if (l < 180 && m < 181) t[ty+8*q][tx] = c2[(long long)l*92672 + cs*181 + m];
    }
    __syncthreads();
    #pragma unroll
    for (int q=0;q<4;q++){
        int m = m0+ty+8*q, l = l0+tx;
        if (m < 181 && l < 180) c3[(long long)m*98304 + cs*192 + l] = t[tx][ty+8*q];
    }
}

// Z [m][o2][180(h)] -> XI [(c*180+h)][384 (s*181+m)] ; m0==160 blocks also
// zero cols [362,384) for their h-range (zero_xi merged here)
__global__ __launch_bounds__(256) void p2_k(const _Float16* Z, _Float16* XI){
    __shared__ _Float16 t[32][33];
    int cs = blockIdx.z; int c = cs & 255, s = cs >> 8;
    int m0 = blockIdx.x*32, h0 = blockIdx.y*32;
    int tx = threadIdx.x & 31, ty = threadIdx.x >> 5;
    #pragma unroll
    for (int q=0;q<4;q++){
        int m = m0+ty+8*q, h = h0+tx;
        if (m < 181 && h < 180) t[ty+8*q][tx] = Z[(long long)m*92160 + cs*180 + h];
    }
    __syncthreads();
    #pragma unroll
    for (int q=0;q<4;q++){
        int h = h0+ty+8*q, m = m0+tx;
        if (h < 180 && m < 181) XI[((long long)c*180 + h)*384 + s*181 + m] = t[tx][ty+8*q];
    }
    if (m0 == 160 && s == 1){
        for (int e = threadIdx.x; e < 704; e += 256){
            int h = h0 + e/22, col = 362 + e%22;
            if (h < 180) XI[((long long)c*180 + h)*384 + col] = (_Float16)0.f;
        }
    }
}

extern "C" void kernel_launch(void* const* d_in, const int* in_sizes, int n_in,
                              void* d_out, int out_size, void* d_ws, size_t ws_size,
                              hipStream_t stream){
    const float* x      = (const float*)d_in[0];
    const float* pct    = (const float*)d_in[1];
    const float* pctinv = (const float*)d_in[2];
    const float* wspec  = (const float*)d_in[3];
    const float* winner = (const float*)d_in[4];
    const float* wfc1   = (const float*)d_in[5];
    const float* wfc2   = (const float*)d_in[6];
    const float* wout   = (const float*)d_in[7];
    float* outp = (float*)d_out;

    _Float16* wsh = (_Float16*)d_ws;
    _Float16* Wc       = wsh;                    // 47,185,920
    _Float16* X_t      = wsh + 47185920LL;       // 16,588,800
    _Float16* Xc       = wsh + 63774720LL;       // 17,694,720
    _Float16* P        = wsh + 81469440LL;       // 17,793,024 xfm / c3
    _Float16* R5       = wsh + 99262464LL;       // 33,361,920 spec / XI / Y_t
    _Float16* R6       = wsh + 132624384LL;      // 16,680,960 c2 / Z / Yc
    _Float16* R7       = wsh + 149305344LL;      // 33,177,600 H_t
    _Float16* pct16    = wsh + 182482944LL;      // 6,255,360
    _Float16* pctinvT  = wsh + 188738304LL;      // 6,255,360
    _Float16* fwdTwT   = wsh + 194993664LL;      // 147,456
    _Float16* invTwT   = wsh + 195141120LL;      // 147,456
    _Float16* winner16 = wsh + 195288576LL;      // 131,072
    _Float16* wfc116   = wsh + 195419648LL;      // 262,144
    _Float16* wfc216   = wsh + 195681792LL;      // 262,144
    _Float16* wout16   = wsh + 195943936LL;      // 32,768

    // ---- setup ----
    setup_misc_k<<<5976, 256, 0, stream>>>(winner, wfc1, wfc2, wout,
        winner16, wfc116, wfc216, wout16, fwdTwT, invTwT, Xc, P);
    tx_k<<<dim3(2025,8), 256, 0, stream>>>(x, X_t, Xc);
    cvt_pct_k<<<24435, 256, 0, stream>>>(pct, pct16);
    cvt_pctinvT_k<<<dim3(6,6,181), 256, 0, stream>>>(pctinv, pctinvT);
    build_wc_k<<<dim3(256,8,12), 256, 0, stream>>>(wspec, Wc);

    for (int layer = 0; layer < 2; layer++){
        _Float16 *xfm = P, *spec = R5, *c2 = R6, *c3 = P;
        _Float16 *Z = R6, *XI = R5, *Yc = R6, *Y_t = R5, *H_t = R7;
        GemmP p; p.C2 = nullptr; p.D = nullptr; p.ldd = 0;

        // DFT fused P1: Xc [46080][384] x fwdTwT [362][384] -> xfm [m][2c+s][192]
        p.A = Xc; p.Bt = fwdTwT; p.C = xfm;
        p.aBS = 0; p.bBS = 0; p.cBS = 0;
        p.lda = 384; p.ldb = 384; p.ldc = 0;
        p.I = 46080; p.J = 362; p.K = 384;
        mfma_gemm<4,0,_Float16,false><<<dim3(3,360,1), 256, 0, stream>>>(p);

        // fwd Legendre (batch m): pct16[m][180 l][192] x xfm[m][512][192]
        //   -> spec [l][362 rows][512]: rows 0-180 signed, 181-361 dual
        p.A = pct16; p.Bt = xfm; p.C = spec; p.C2 = spec + 92672;
        p.aBS = 34560; p.bBS = 98304; p.cBS = 512;
        p.lda = 192; p.ldb = 192; p.ldc = 185344;
        p.I = 180; p.J = 512; p.K = 192;
        mfma_gemm<2,0,_Float16,false><<<dim3(4,2,181), 256, 0, stream>>>(p);
        p.C2 = nullptr;

        // dhconv (batch l): Wc[l][256][512] x spec[l][362][512] -> c2 [l][512 o2][181 m]
        p.A = Wc + (long long)layer*23592960LL; p.Bt = spec; p.C = c2;
        p.aBS = 131072; p.bBS = 185344; p.cBS = 92672;
        p.lda = 512; p.ldb = 512; p.ldc = 181;
        p.I = 256; p.J = 362; p.K = 512;
        mfma_gemm<3,0,_Float16,false><<<dim3(3,2,180), 256, 0, stream>>>(p);

        // permute: c2 -> c3 [m][o2][192(l)]
        plm_k<<<dim3(6,6,512), 256, 0, stream>>>(c2, c3);

        // inv Legendre (batch m): c3[m][512][192] x pctinvT[m][180 h][192] -> Z [m][o2][h]
        p.A = c3; p.Bt = pctinvT; p.C = Z;
        p.aBS = 98304; p.bBS = 34560; p.cBS = 92160;
        p.lda = 192; p.ldb = 192; p.ldc = 180;
        p.I = 512; p.J = 180; p.K = 192;
        mfma_gemm<0,0,_Float16,false><<<dim3(2,4,181), 256, 0, stream>>>(p);

        // P2 (+pad-zero): Z -> XI [(c,h)][384]
        p2_k<<<dim3(6,6,512), 256, 0, stream>>>(Z, XI);

        // iDFT: XI [46080][384] x invTwT [360][384] -> Yc [46080][360]
        p.A = XI; p.Bt = invTwT; p.C = Yc;
        p.aBS = 0; p.bBS = 0; p.cBS = 0;
        p.lda = 384; p.ldb = 384; p.ldc = 360;
        p.I = 46080; p.J = 360; p.K = 384;
        mfma_gemm<0,0,_Float16,false><<<dim3(3,360,1), 256, 0, stream>>>(p);

        // inner skip: Y_t[hw][256] = gelu(winner@X_t + Yc)   (GSW: x=bi)
        p.A = winner16 + (long long)layer*65536; p.Bt = X_t; p.C = Y_t;
        p.D = Yc; p.ldd = 64800;
        p.lda = 256; p.ldb = 256; p.ldc = 256;
        p.I = 256; p.J = 64800; p.K = 256;
        mfma_gemm<1,5,_Float16,true><<<dim3(2,507,1), 256, 0, stream>>>(p);
        p.D = nullptr; p.ldd = 0;

        // fc1 + gelu -> H_t [hw][512]
        p.A = wfc116 + (long long)layer*131072; p.Bt = Y_t; p.C = H_t;
        p.lda = 256; p.ldb = 256; p.ldc = 512;
        p.I = 512; p.J = 64800; p.K = 256;
        mfma_gemm<1,1,_Float16,true><<<dim3(4,507,1), 256, 0, stream>>>(p);

        // fc2 + residual + gelu -> X_t ; layer 0 also dual-stores next Xc
        p.A = wfc216 + (long long)layer*131072; p.Bt = H_t; p.C = X_t;
        p.lda = 512; p.ldb = 512; p.ldc = 256;
        p.I = 256; p.J = 64800; p.K = 512;
        if (layer == 0){
            p.C2 = Xc;
            mfma_gemm<1,11,_Float16,true><<<dim3(2,507,1), 256, 0, stream>>>(p);
            p.C2 = nullptr;
        } else {
            mfma_gemm<1,3,_Float16,true><<<dim3(2,507,1), 256, 0, stream>>>(p);
        }
    }

    // final: wout16 [128][256] x X_t -> d_out f32 [128][64800]
    GemmP p; p.C2 = nullptr; p.D = nullptr; p.ldd = 0;
    p.A = wout16; p.Bt = X_t; p.C = outp;
    p.aBS = 0; p.bBS = 0; p.cBS = 0;
    p.lda = 256; p.ldb = 256; p.ldc = 64800;
    p.I = 128; p.J = 64800; p.K = 256;
    mfma_gemm<0,0,float,true><<<dim3(1,507,1), 256, 0, stream>>>(p);
}

// Round 10
// 962.770 us; speedup vs baseline: 1.1677x; 1.1677x over previous
//
#include <hip/hip_runtime.h>
#include <hip/hip_bf16.h>
#include <math.h>

typedef _Float16 half8 __attribute__((ext_vector_type(8)));
typedef _Float16 half4v __attribute__((ext_vector_type(4)));
typedef float floatx4 __attribute__((ext_vector_type(4)));

// tanh-gelu as x*sigmoid(2*0.7978845608*(x+0.044715 x^3));
// max |dev| vs exact erf-gelu ~3e-3 (invisible vs 9.56e-2 threshold at f16).
// ~7 VALU ops vs ~14 for A&S erf -> halves the epilogue VALU cost.
__device__ __forceinline__ float gelu_f(float x){
    float x2 = x * x;
    float u  = x * (1.5957691216f + 0.0713548163f * x2);
    float e  = __expf(-u);
    return x / (1.0f + e);
}

typedef __attribute__((address_space(1))) const unsigned int gu32;
typedef __attribute__((address_space(3))) unsigned int lu32;
__device__ __forceinline__ void gl16(const void* g, void* l){
    __builtin_amdgcn_global_load_lds((gu32*)g, (lu32*)l, 16, 0, 0);
}

// ---------------- generic f16 MFMA GEMM (BK=64) ----------------
// C[i][j] = sum_k A[i][k] * Bt[j][k]   (A,Bt rows 16B-aligned, K % 64 == 0,
// all K-tail/pad regions of A,Bt are ZERO; OOB rows readable garbage)
// BK=64: per K-step 8x global_load_lds + 32 MFMA between one barrier pair.
// LDS swizzle (rule #21): linear LDS dest (gload_lds), SOURCE chunk
// pre-swizzled (lane&7)^(row&7); reader chunk ((ks*4+lb)^(la&7)).
// SM: 0 row store C[i*ldc+j]
//     1 trans store C[j*ldc+i..i+3] (EPI bits: 1 gelu, 2 +C-old, 4 +D, 8 dual Xc)
//     2 spec-dual (fwd Legendre): C row j signed, C2 row j^1
//     3 dhconv-split: j<181 -> row i col j ; j>=181 -> row i+256 col j-181
//     4 DFT->xfm fused: xfm[m][2c+s][192] from i=(c,h), j=(s,m)
// Fusion rule (R5): epilogue may deviate from row-major ONLY if each block's
// output footprint covers whole 64B lines.
struct GemmP {
    const _Float16* A; const _Float16* Bt; void* C; void* C2; const _Float16* D;
    long long aBS, bBS, cBS;
    int lda, ldb, ldc, ldd;
    int I, J, K;
};

template<int SM, int EPI, typename CT, bool GSW>
__global__ __launch_bounds__(256, 3) void mfma_gemm(GemmP p){
    __shared__ __align__(16) _Float16 As[128][64];
    __shared__ __align__(16) _Float16 Bs[128][64];
    const int tid = threadIdx.x, lane = tid & 63, wave = tid >> 6;
    const int wr = wave >> 1, wc = wave & 1;
    const int bj = GSW ? blockIdx.y : blockIdx.x;
    const int bi = GSW ? blockIdx.x : blockIdx.y;
    const int bz = blockIdx.z;
    const _Float16* A  = p.A  + (long long)bz * p.aBS;
    const _Float16* Bt = p.Bt + (long long)bz * p.bBS;
    CT* C = (CT*)p.C + (long long)bz * p.cBS;

    const int srow = tid >> 3;                       // 0..31
    const int cg = ((tid & 7) ^ (srow & 7)) * 8;     // inverse-swizzled source chunk
    const _Float16* Ag = A  + (long long)(bi*128 + srow)*p.lda + cg;
    const _Float16* Bg = Bt + (long long)(bj*128 + srow)*p.ldb + cg;
    const long long a32 = (long long)32 * p.lda, b32 = (long long)32 * p.ldb;
    _Float16* AsW = &As[0][0] + wave*512;            // wave-uniform base (1024 B/wave)
    _Float16* BsW = &Bs[0][0] + wave*512;

    floatx4 acc[4][4];
    #pragma unroll
    for (int a=0;a<4;a++)
        #pragma unroll
        for (int b=0;b<4;b++) acc[a][b] = (floatx4){0.f,0.f,0.f,0.f};

    const int la = lane & 15, lb = lane >> 4;

    for (int k0 = 0; k0 < p.K; k0 += 64){
        #pragma unroll
        for (int it=0; it<4; it++){
            gl16(Ag + k0 + it*a32, AsW + it*2048);
            gl16(Bg + k0 + it*b32, BsW + it*2048);
        }
        __syncthreads();

        #pragma unroll
        for (int ks=0; ks<2; ks++){
            const int ca = (((ks<<2) | lb) ^ (la & 7)) * 8;   // swizzled read col
            half8 af[4], bf[4];
            #pragma unroll
            for (int f=0; f<4; f++) af[f] = *(const half8*)&As[wr*64 + f*16 + la][ca];
            #pragma unroll
            for (int f=0; f<4; f++) bf[f] = *(const half8*)&Bs[wc*64 + f*16 + la][ca];
            #pragma unroll
            for (int mi=0; mi<4; mi++)
                #pragma unroll
                for (int nj=0; nj<4; nj++)
                    acc[mi][nj] = __builtin_amdgcn_mfma_f32_16x16x32_f16(
                        af[mi], bf[nj], acc[mi][nj], 0, 0, 0);
        }
        __syncthreads();
    }

    // epilogue. C/D: col = lane&15, row = (lane>>4)*4 + reg
    #pragma unroll
    for (int mi=0; mi<4; mi++){
        const int ibase = bi*128 + wr*64 + mi*16 + lb*4;
        #pragma unroll
        for (int nj=0; nj<4; nj++){
            const int j = bj*128 + wc*64 + nj*16 + la;
            if (j >= p.J) continue;
            if (SM == 0){
                #pragma unroll
                for (int r=0;r<4;r++){
                    int i = ibase + r;
                    if (i >= p.I) continue;
                    C[(long long)i*p.ldc + j] = (CT)acc[mi][nj][r];
                }
            } else if (SM == 2){
                _Float16* C2p = (_Float16*)p.C2 + (long long)bz*p.cBS;
                #pragma unroll
                for (int r=0;r<4;r++){
                    int i = ibase + r;
                    if (i >= p.I) continue;
                    float v = acc[mi][nj][r];
                    ((_Float16*)C)[(long long)i*p.ldc + j]   = (_Float16)((j & 1) ? -v : v);
                    C2p[(long long)i*p.ldc + (j ^ 1)]        = (_Float16)v;
                }
            } else if (SM == 3){
                const int row_add = (j < 181) ? 0 : 256;
                const int col = (j < 181) ? j : j - 181;
                #pragma unroll
                for (int r=0;r<4;r++){
                    int i = ibase + r;
                    if (i >= p.I) continue;
                    C[(long long)(i + row_add)*p.ldc + col] = (CT)acc[mi][nj][r];
                }
            } else if (SM == 4){
                // i = c*180+h (groups of 4 never cross c), j = s*181+m
                const int s = (j < 181) ? 0 : 1;
                const int m = j - s*181;
                const int c = ibase / 180, h0 = ibase % 180;
                half4v ov;
                #pragma unroll
                for (int r=0;r<4;r++) ov[r] = (_Float16)acc[mi][nj][r];
                *(half4v*)(void*)&((_Float16*)C)[(long long)m*98304 + (2*c + s)*192 + h0] = ov;
            } else { // SM == 1
                CT* cp = C + (long long)j*p.ldc + ibase;
                float v[4];
                #pragma unroll
                for (int r=0;r<4;r++) v[r] = acc[mi][nj][r];
                if (EPI & 2){
                    half4v old = *(const half4v*)(const void*)cp;
                    #pragma unroll
                    for (int r=0;r<4;r++) v[r] += (float)old[r];
                }
                if (EPI & 4){
                    #pragma unroll
                    for (int r=0;r<4;r++)
                        v[r] += (float)p.D[(long long)(ibase + r)*p.ldd + j];
                }
                if (EPI & 1){
                    #pragma unroll
                    for (int r=0;r<4;r++) v[r] = gelu_f(v[r]);
                }
                half4v ov;
                #pragma unroll
                for (int r=0;r<4;r++) ov[r] = (_Float16)v[r];
                *(half4v*)(void*)cp = ov;
                if (EPI & 8){
                    int h = j/360, w = j - h*360;
                    _Float16* xc = (_Float16*)p.C2;
                    #pragma unroll
                    for (int r=0;r<4;r++)
                        xc[(long long)(ibase + r)*69120 + h*384 + w] = ov[r];
                }
            }
        }
    }
}

// ---------------- setup / bridge kernels ----------------
// x f32 [c][hw] -> X_t f16 [hw][256] AND Xc f16 [(c*180+h)][384]
__global__ __launch_bounds__(256) void tx_k(const float* x, _Float16* X_t, _Float16* Xc){
    __shared__ _Float16 t[32][33];
    int p0 = blockIdx.x*32, c0 = blockIdx.y*32;
    int tx = threadIdx.x & 31, ty = threadIdx.x >> 5;
    #pragma unroll
    for (int q=0;q<4;q++){
        int c = c0 + ty + 8*q, hw = p0 + tx;
        _Float16 h = (_Float16)x[(long long)c*64800 + hw];
        t[ty+8*q][tx] = h;
        int hh = hw/360, w = hw - hh*360;
        Xc[((long long)c*180 + hh)*384 + w] = h;
    }
    __syncthreads();
    #pragma unroll
    for (int q=0;q<4;q++){
        int hw = p0 + ty + 8*q, c = c0 + tx;
        X_t[(long long)hw*256 + c] = t[tx][ty+8*q];
    }
}

// merged small setup: tw tables + Xc pad + P pad + 4 weight casts
__global__ __launch_bounds__(256) void setup_misc_k(
        const float* winner, const float* wfc1, const float* wfc2, const float* wout,
        _Float16* winner16, _Float16* wfc116, _Float16* wfc216, _Float16* wout16,
        _Float16* fwdTwT, _Float16* invTwT, _Float16* Xc, _Float16* P){
    int id = blockIdx.x*256 + threadIdx.x;
    if (id < 147456){
        {
            int j = id / 384, w = id % 384;
            float v = 0.f;
            if (j < 362 && w < 360){
                int m = (j < 181) ? j : j - 181;
                float ang = 6.28318530717958647692f * (float)((w*m) % 360) / 360.f;
                v = (j < 181) ? cosf(ang) : -sinf(ang);
            }
            fwdTwT[id] = (_Float16)v;
        }
        {
            int w = id / 384, k = id % 384;
            float v = 0.f;
            if (w < 360 && k < 362){
                int m = (k < 181) ? k : k - 181;
                float ang = 6.28318530717958647692f * (float)((w*m) % 360) / 360.f;
                float sc = (m == 0 || m == 180) ? (1.f/360.f) : (2.f/360.f);
                v = (k < 181) ? sc*cosf(ang) : -sc*sinf(ang);
            }
            invTwT[id] = (_Float16)v;
        }
        return;
    }
    int a = id - 147456;
    if (a < 138240){
        int row = a/3, c = a - 3*row;
        *(uint4*)&Xc[(long long)row*384 + 360 + c*8] = make_uint4(0u,0u,0u,0u);
        return;
    }
    int b = a - 138240;
    if (b < 556032){
        int row = b/6, c = b - 6*row;
        *(unsigned int*)&P[(long long)row*192 + 180 + c*2] = 0u;
        return;
    }
    int c = b - 556032;
    if (c < 131072){ winner16[c] = (_Float16)winner[c]; return; }
    c -= 131072;
    if (c < 262144){ wfc116[c] = (_Float16)wfc1[c]; return; }
    c -= 262144;
    if (c < 262144){ wfc216[c] = (_Float16)wfc2[c]; return; }
    c -= 262144;
    if (c < 32768){ wout16[c] = (_Float16)wout[c]; }
}

// pct [m][l][h] f32 -> pct16 [m][l][192] (pad zero)
__global__ __launch_bounds__(256) void cvt_pct_k(const float* in, _Float16* out){
    int id = blockIdx.x*256 + threadIdx.x;
    if (id >= 181*180*192) return;
    int m = id / 34560, r = id % 34560;
    int l = r / 192, h = r % 192;
    out[id] = (h < 180) ? (_Float16)in[(long long)m*32400 + l*180 + h] : (_Float16)0.f;
}

// pctinv [m][l][h] -> pctinvT [m][h][192(l)] (pad zero)
__global__ __launch_bounds__(256) void cvt_pctinvT_k(const float* in, _Float16* out){
    __shared__ float t[32][33];
    int m = blockIdx.z;
    int h0 = blockIdx.x*32, l0 = blockIdx.y*32;
    int tx = threadIdx.x & 31, ty = threadIdx.x >> 5;
    #pragma unroll
    for (int q=0;q<4;q++){
        int l = l0+ty+8*q, h = h0+tx;
        t[ty+8*q][tx] = (l < 180 && h < 180) ? in[(long long)m*32400 + l*180 + h] : 0.f;
    }
    __syncthreads();
    #pragma unroll
    for (int q=0;q<4;q++){
        int h = h0+ty+8*q, l = l0+tx;
        if (h < 180 && l < 192) out[(long long)m*34560 + h*192 + l] = (_Float16)t[tx][ty+8*q];
    }
}

// wspec [layer][ci][o][l][s] f32 -> Wc u32 view [((layer*180+l)*256+o)*256+ci] = half2(re,im)
__global__ __launch_bounds__(256) void build_wc_k(const float* wspec, _Float16* Wc){
    __shared__ unsigned int t[32][33];
    int o = blockIdx.x;
    int ci0 = blockIdx.y * 32;
    int z = blockIdx.z, layer = z / 6, l0 = (z % 6) * 32;
    int tx = threadIdx.x & 31, ty = threadIdx.x >> 5;
    unsigned int* Wc32 = (unsigned int*)Wc;
    #pragma unroll
    for (int q=0;q<4;q++){
        int ci = ci0 + ty + 8*q, l = l0 + tx;
        if (l < 180){
            const float2 v = *(const float2*)(wspec +
                ((long long)(layer*256 + ci))*92160 + (long long)o*360 + 2*l);
            union { unsigned int u; _Float16 h[2]; } pk;
            pk.h[0] = (_Float16)v.x; pk.h[1] = (_Float16)v.y;
            t[ty+8*q][tx] = pk.u;
        }
    }
    __syncthreads();
    #pragma unroll
    for (int q=0;q<4;q++){
        int l = l0 + ty + 8*q, ci = ci0 + tx;
        if (l < 180)
            Wc32[(((long long)layer*180 + l)*256 + o)*256 + ci] = t[tx][ty+8*q];
    }
}

// c2 [l][o2][m] (ld 181) -> c3 [m][o2][192(l)]
__global__ __launch_bounds__(256) void plm_k(const _Float16* c2, _Float16* c3){
    __shared__ _Float16 t[32][33];
    int cs = blockIdx.z;
    int m0 = blockIdx.x*32, l0 = blockIdx.y*32;
    int tx = threadIdx.x & 31, ty = threadIdx.x >> 5;
    #pragma unroll
    for (int q=0;q<4;q++){
        int l = l0+ty+8*q, m = m0+tx;
        if (l < 180 && m < 181) t[ty+8*q][tx] = c2[(long long)l*92672 + cs*181 + m];
    }
    __syncthreads();
    #pragma unroll
    for (int q=0;q<4;q++){
        int m = m0+ty+8*q, l = l0+tx;
        if (m < 181 && l < 180) c3[(long long)m*98304 + cs*192 + l] = t[tx][ty+8*q];
    }
}

// Z [m][o2][180(h)] -> XI [(c*180+h)][384 (s*181+m)] ; m0==160,s==1 blocks also
// zero cols [362,384) for their h-range
__global__ __launch_bounds__(256) void p2_k(const _Float16* Z, _Float16* XI){
    __shared__ _Float16 t[32][33];
    int cs = blockIdx.z; int c = cs & 255, s = cs >> 8;
    int m0 = blockIdx.x*32, h0 = blockIdx.y*32;
    int tx = threadIdx.x & 31, ty = threadIdx.x >> 5;
    #pragma unroll
    for (int q=0;q<4;q++){
        int m = m0+ty+8*q, h = h0+tx;
        if (m < 181 && h < 180) t[ty+8*q][tx] = Z[(long long)m*92160 + cs*180 + h];
    }
    __syncthreads();
    #pragma unroll
    for (int q=0;q<4;q++){
        int h = h0+ty+8*q, m = m0+tx;
        if (h < 180 && m < 181) XI[((long long)c*180 + h)*384 + s*181 + m] = t[tx][ty+8*q];
    }
    if (m0 == 160 && s == 1){
        for (int e = threadIdx.x; e < 704; e += 256){
            int h = h0 + e/22, col = 362 + e%22;
            if (h < 180) XI[((long long)c*180 + h)*384 + col] = (_Float16)0.f;
        }
    }
}

extern "C" void kernel_launch(void* const* d_in, const int* in_sizes, int n_in,
                              void* d_out, int out_size, void* d_ws, size_t ws_size,
                              hipStream_t stream){
    const float* x      = (const float*)d_in[0];
    const float* pct    = (const float*)d_in[1];
    const float* pctinv = (const float*)d_in[2];
    const float* wspec  = (const float*)d_in[3];
    const float* winner = (const float*)d_in[4];
    const float* wfc1   = (const float*)d_in[5];
    const float* wfc2   = (const float*)d_in[6];
    const float* wout   = (const float*)d_in[7];
    float* outp = (float*)d_out;

    _Float16* wsh = (_Float16*)d_ws;
    _Float16* Wc       = wsh;                    // 47,185,920
    _Float16* X_t      = wsh + 47185920LL;       // 16,588,800
    _Float16* Xc       = wsh + 63774720LL;       // 17,694,720
    _Float16* P        = wsh + 81469440LL;       // 17,793,024 xfm / c3
    _Float16* R5       = wsh + 99262464LL;       // 33,361,920 spec / XI / Y_t
    _Float16* R6       = wsh + 132624384LL;      // 16,680,960 c2 / Z / Yc
    _Float16* R7       = wsh + 149305344LL;      // 33,177,600 H_t
    _Float16* pct16    = wsh + 182482944LL;      // 6,255,360
    _Float16* pctinvT  = wsh + 188738304LL;      // 6,255,360
    _Float16* fwdTwT   = wsh + 194993664LL;      // 147,456
    _Float16* invTwT   = wsh + 195141120LL;      // 147,456
    _Float16* winner16 = wsh + 195288576LL;      // 131,072
    _Float16* wfc116   = wsh + 195419648LL;      // 262,144
    _Float16* wfc216   = wsh + 195681792LL;      // 262,144
    _Float16* wout16   = wsh + 195943936LL;      // 32,768

    // ---- setup ----
    setup_misc_k<<<5976, 256, 0, stream>>>(winner, wfc1, wfc2, wout,
        winner16, wfc116, wfc216, wout16, fwdTwT, invTwT, Xc, P);
    tx_k<<<dim3(2025,8), 256, 0, stream>>>(x, X_t, Xc);
    cvt_pct_k<<<24435, 256, 0, stream>>>(pct, pct16);
    cvt_pctinvT_k<<<dim3(6,6,181), 256, 0, stream>>>(pctinv, pctinvT);
    build_wc_k<<<dim3(256,8,12), 256, 0, stream>>>(wspec, Wc);

    for (int layer = 0; layer < 2; layer++){
        _Float16 *xfm = P, *spec = R5, *c2 = R6, *c3 = P;
        _Float16 *Z = R6, *XI = R5, *Yc = R6, *Y_t = R5, *H_t = R7;
        GemmP p; p.C2 = nullptr; p.D = nullptr; p.ldd = 0;

        // DFT fused P1: Xc [46080][384] x fwdTwT [362][384] -> xfm [m][2c+s][192]
        p.A = Xc; p.Bt = fwdTwT; p.C = xfm;
        p.aBS = 0; p.bBS = 0; p.cBS = 0;
        p.lda = 384; p.ldb = 384; p.ldc = 0;
        p.I = 46080; p.J = 362; p.K = 384;
        mfma_gemm<4,0,_Float16,false><<<dim3(3,360,1), 256, 0, stream>>>(p);

        // fwd Legendre (batch m): pct16[m][180 l][192] x xfm[m][512][192]
        //   -> spec [l][362 rows][512]: rows 0-180 signed, 181-361 dual
        p.A = pct16; p.Bt = xfm; p.C = spec; p.C2 = spec + 92672;
        p.aBS = 34560; p.bBS = 98304; p.cBS = 512;
        p.lda = 192; p.ldb = 192; p.ldc = 185344;
        p.I = 180; p.J = 512; p.K = 192;
        mfma_gemm<2,0,_Float16,false><<<dim3(4,2,181), 256, 0, stream>>>(p);
        p.C2 = nullptr;

        // dhconv (batch l): Wc[l][256][512] x spec[l][362][512] -> c2 [l][512 o2][181 m]
        p.A = Wc + (long long)layer*23592960LL; p.Bt = spec; p.C = c2;
        p.aBS = 131072; p.bBS = 185344; p.cBS = 92672;
        p.lda = 512; p.ldb = 512; p.ldc = 181;
        p.I = 256; p.J = 362; p.K = 512;
        mfma_gemm<3,0,_Float16,false><<<dim3(3,2,180), 256, 0, stream>>>(p);

        // permute: c2 -> c3 [m][o2][192(l)]
        plm_k<<<dim3(6,6,512), 256, 0, stream>>>(c2, c3);

        // inv Legendre (batch m): c3[m][512][192] x pctinvT[m][180 h][192] -> Z [m][o2][h]
        p.A = c3; p.Bt = pctinvT; p.C = Z;
        p.aBS = 98304; p.bBS = 34560; p.cBS = 92160;
        p.lda = 192; p.ldb = 192; p.ldc = 180;
        p.I = 512; p.J = 180; p.K = 192;
        mfma_gemm<0,0,_Float16,false><<<dim3(2,4,181), 256, 0, stream>>>(p);

        // P2 (+pad-zero): Z -> XI [(c,h)][384]
        p2_k<<<dim3(6,6,512), 256, 0, stream>>>(Z, XI);

        // iDFT: XI [46080][384] x invTwT [360][384] -> Yc [46080][360]
        p.A = XI; p.Bt = invTwT; p.C = Yc;
        p.aBS = 0; p.bBS = 0; p.cBS = 0;
        p.lda = 384; p.ldb = 384; p.ldc = 360;
        p.I = 46080; p.J = 360; p.K = 384;
        mfma_gemm<0,0,_Float16,false><<<dim3(3,360,1), 256, 0, stream>>>(p);

        // inner skip: Y_t[hw][256] = gelu(winner@X_t + Yc)   (GSW: x=bi)
        p.A = winner16 + (long long)layer*65536; p.Bt = X_t; p.C = Y_t;
        p.D = Yc; p.ldd = 64800;
        p.lda = 256; p.ldb = 256; p.ldc = 256;
        p.I = 256; p.J = 64800; p.K = 256;
        mfma_gemm<1,5,_Float16,true><<<dim3(2,507,1), 256, 0, stream>>>(p);
        p.D = nullptr; p.ldd = 0;

        // fc1 + gelu -> H_t [hw][512]
        p.A = wfc116 + (long long)layer*131072; p.Bt = Y_t; p.C = H_t;
        p.lda = 256; p.ldb = 256; p.ldc = 512;
        p.I = 512; p.J = 64800; p.K = 256;
        mfma_gemm<1,1,_Float16,true><<<dim3(4,507,1), 256, 0, stream>>>(p);

        // fc2 + residual + gelu -> X_t ; layer 0 also dual-stores next Xc
        p.A = wfc216 + (long long)layer*131072; p.Bt = H_t; p.C = X_t;
        p.lda = 512; p.ldb = 512; p.ldc = 256;
        p.I = 256; p.J = 64800; p.K = 512;
        if (layer == 0){
            p.C2 = Xc;
            mfma_gemm<1,11,_Float16,true><<<dim3(2,507,1), 256, 0, stream>>>(p);
            p.C2 = nullptr;
        } else {
            mfma_gemm<1,3,_Float16,true><<<dim3(2,507,1), 256, 0, stream>>>(p);
        }
    }

    // final: wout16 [128][256] x X_t -> d_out f32 [128][64800]
    GemmP p; p.C2 = nullptr; p.D = nullptr; p.ldd = 0;
    p.A = wout16; p.Bt = X_t; p.C = outp;
    p.aBS = 0; p.bBS = 0; p.cBS = 0;
    p.lda = 256; p.ldb = 256; p.ldc = 64800;
    p.I = 128; p.J = 64800; p.K = 256;
    mfma_gemm<0,0,float,true><<<dim3(1,507,1), 256, 0, stream>>>(p);
}